// Round 5
// baseline (288.637 us; speedup 1.0000x reference)
//
#include <hip/hip_runtime.h>
#include <stdint.h>

#define B_ 2048
#define T_ 256
#define V_ 128
#define E_ 128
#define H_ 64
#define G4_ 256  // 4*H
#define POS_W 20.0f
#define MB_ 4            // batch rows per wave-block (M-rows 4*hi, C-reg[0])
#define NBLK_ (B_ / MB_) // 512 blocks of ONE wave each: no barriers anywhere
typedef _Float16 half1;
typedef __attribute__((ext_vector_type(8))) _Float16 f16x8;
typedef __attribute__((ext_vector_type(4))) float f32x4;
typedef __attribute__((ext_vector_type(4))) int i32x4;

#if __has_builtin(__builtin_amdgcn_exp2f)
#define EXP2F(x) __builtin_amdgcn_exp2f(x)
#else
#define EXP2F(x) exp2f(x)
#endif

#if __has_builtin(__builtin_amdgcn_rcpf)
#define RCPF(x) __builtin_amdgcn_rcpf(x)
#else
#define RCPF(x) (1.0f / (x))
#endif

__device__ __forceinline__ float tanhr(float x) {
    // tanh(x) = 1 - 2/(e^(2x)+1); exp2 over/underflow saturates correctly
    float t = EXP2F(2.88539008f * x);
    return 1.0f - 2.0f * RCPF(t + 1.0f);
}

__device__ __forceinline__ unsigned f16bits(half1 h) {
    union { half1 h; unsigned short u; } v;
    v.h = h;
    return (unsigned)v.u;
}

// ---------------------------------------------------------------------------
// k_prep: projC[v][u][g] = dot(emb[v], W_ih[g*64+u]) + b_ih + b_hh   (f32)
// Layout [v][unit][gate]: LSTM kernel gathers one float4 per (v,unit).
// Block 0 / tid 0 zeroes the loss accumulator.
// ---------------------------------------------------------------------------
__global__ void k_prep(const float* __restrict__ emb, const float* __restrict__ Wih,
                       const float* __restrict__ bih, const float* __restrict__ bhh,
                       float* __restrict__ projC, float* __restrict__ loss_slot) {
    int tid = threadIdx.x;  // 0..255; u = tid>>2, g = tid&3
    int v = blockIdx.x;
    if (v == 0 && tid == 0) *loss_slot = 0.0f;
    int u = tid >> 2, g = tid & 3;
    int row = g * 64 + u;
    const float4* e4 = (const float4*)(emb + v * E_);
    const float4* w4 = (const float4*)(Wih + row * E_);
    float acc = bih[row] + bhh[row];
#pragma unroll
    for (int i = 0; i < E_ / 4; ++i) {
        float4 a = e4[i];
        float4 b = w4[i];
        acc += a.x * b.x + a.y * b.y + a.z * b.z + a.w * b.w;
    }
    projC[v * G4_ + tid] = acc;  // coalesced
}

// ---------------------------------------------------------------------------
// k_lstm R13: BARRIER-FREE wave-local recurrence.
// One 64-lane wave per 4 batch rows. The wave computes ALL 64 units:
//   16 MFMA-pairs/step (4 gates x 4 N-tiles, K=64 chained through C).
//   D[4*hi][cc] => lane (hi,cc) owns batch row hi, units {16n+cc, n=0..3}.
// h-exchange for next step's A-fragment is an IN-WAVE transpose:
//   pack 4 f32 h -> 2x(f16x2), 16 ds_bpermute (8 loop-invariant addrs:
//   src lane = 16*(cc>>2) + (hi&1)*8 + j), half-select n=hi>>1 via v_perm.
// No s_barrier, no LDS h buffer, no cross-wave dependency of any kind.
// proj bias folds into the exp2 args via fma (pre-scaled off-chain).
// ---------------------------------------------------------------------------
__launch_bounds__(64, 1)
__global__ void k_lstm(const int* __restrict__ x, const float* __restrict__ Whh,
                       const float* __restrict__ projC, const float* __restrict__ Wfc,
                       const float* __restrict__ bfc, const float* __restrict__ targets,
                       float* __restrict__ logits, float* __restrict__ loss_slot) {
    int b0 = blockIdx.x * MB_;
    int l = threadIdx.x;          // 0..63
    int hi = l >> 4, cc = l & 15; // lane owns batch row hi, units 16n+cc

    __shared__ int xT[T_][MB_];  // token byte-offsets (tok<<10)
    for (int i = l; i < T_ * MB_; i += 64) {
        int tt = i >> 2, rr = i & 3;
        xT[tt][rr] = x[(b0 + rr) * T_ + tt] << 10;  // *G4_*4
    }
    __syncthreads();

    // B-fragments from W_hh (f32, L2): gate g, N-tile n, K-chunk c.
    // frag elem j: B[k=c*32+hi*8+j][col cc] = Whh[g*64+16n+cc][k]
    f16x8 bf[4][4][2];
#pragma unroll
    for (int g = 0; g < 4; ++g)
#pragma unroll
        for (int n = 0; n < 4; ++n)
#pragma unroll
            for (int c = 0; c < 2; ++c) {
                int row = g * 64 + 16 * n + cc;
                int kb = c * 32 + hi * 8;
                float4 w0 = *(const float4*)(Whh + row * H_ + kb);
                float4 w1 = *(const float4*)(Whh + row * H_ + kb + 4);
                f16x8 tmp;
                tmp[0] = (half1)w0.x; tmp[1] = (half1)w0.y;
                tmp[2] = (half1)w0.z; tmp[3] = (half1)w0.w;
                tmp[4] = (half1)w1.x; tmp[5] = (half1)w1.y;
                tmp[6] = (half1)w1.z; tmp[7] = (half1)w1.w;
                bf[g][n][c] = tmp;
            }

    // bpermute gather: a0[j] = h_{cc>>2}[hi*8+j], a1[j] = h_{cc>>2}[32+hi*8+j]
    // src lane = 16*(cc>>2) + (hi&1)*8 + j  (byte addr = lane*4), loop-invariant
    int abase = ((cc >> 2) << 6) + ((hi & 1) << 5);
    // half-select n = hi>>1: 0 -> low f16 of each gathered word, 1 -> high
    unsigned sel = (hi & 2) ? 0x07060302u : 0x05040100u;

    const char* pcb = (const char*)projC + cc * 16;  // + tok<<10 + n*256
    float ccell[4] = {0.f, 0.f, 0.f, 0.f};
    float hkeep[4] = {0.f, 0.f, 0.f, 0.f};
    f16x8 a0, a1;
#pragma unroll
    for (int j = 0; j < 8; ++j) { a0[j] = (half1)0.f; a1[j] = (half1)0.f; }

    // proj prefetch depth 1 (L2 latency << step length)
    f32x4 pp[4], pn[4];
    int tok0 = xT[0][hi];
#pragma unroll
    for (int n = 0; n < 4; ++n) pp[n] = *(const f32x4*)(pcb + tok0 + n * 256);
    int xc = xT[1][hi];

    const f32x4 z4 = {0.f, 0.f, 0.f, 0.f};
#pragma unroll 1
    for (int step = 0; step < T_; ++step) {
        // ---- off-chain: prefetch next step's proj + token
#pragma unroll
        for (int n = 0; n < 4; ++n) pn[n] = *(const f32x4*)(pcb + xc + n * 256);
        int xn = xT[(step + 2) & (T_ - 1)][hi];

        // ---- gates: 16 chained MFMA-pairs, C=0 (no per-MFMA C movs)
        float G[4][4];
#pragma unroll
        for (int n = 0; n < 4; ++n)
#pragma unroll
            for (int g = 0; g < 4; ++g) {
                f32x4 d0 = __builtin_amdgcn_mfma_f32_16x16x32_f16(a0, bf[g][n][0], z4, 0, 0, 0);
                f32x4 d = __builtin_amdgcn_mfma_f32_16x16x32_f16(a1, bf[g][n][1], d0, 0, 0, 0);
                G[n][g] = d[0];
            }

        // ---- 4 cell updates; pp folded into exp2 args via fma
        unsigned us[4];
#pragma unroll
        for (int n = 0; n < 4; ++n) {
            float psx = -1.44269504f * pp[n][0];
            float psy = -1.44269504f * pp[n][1];
            float pgz = 2.88539008f * pp[n][2];
            float psw = -1.44269504f * pp[n][3];
            float i_ = RCPF(1.0f + EXP2F(__builtin_fmaf(-1.44269504f, G[n][0], psx)));
            float f_ = RCPF(1.0f + EXP2F(__builtin_fmaf(-1.44269504f, G[n][1], psy)));
            float tg = 1.0f - 2.0f * RCPF(EXP2F(__builtin_fmaf(2.88539008f, G[n][2], pgz)) + 1.0f);
            float o_ = RCPF(1.0f + EXP2F(__builtin_fmaf(-1.44269504f, G[n][3], psw)));
            float cn = __builtin_fmaf(f_, ccell[n], i_ * tg);
            ccell[n] = cn;
            float hn = o_ * tanhr(cn);
            hkeep[n] = hn;
            us[n] = f16bits((half1)hn);
        }
        unsigned hp01 = us[0] | (us[1] << 16);
        unsigned hp23 = us[2] | (us[3] << 16);

        // ---- in-wave transpose -> next A-fragments (no barrier!)
        int r01[8], r23[8];
#pragma unroll
        for (int j = 0; j < 8; ++j) {
            int ad = abase + 4 * j;
            r01[j] = __builtin_amdgcn_ds_bpermute(ad, (int)hp01);
            r23[j] = __builtin_amdgcn_ds_bpermute(ad, (int)hp23);
        }
        i32x4 A0, A1;
#pragma unroll
        for (int k = 0; k < 4; ++k) {
            A0[k] = (int)__builtin_amdgcn_perm((unsigned)r01[2 * k + 1], (unsigned)r01[2 * k], sel);
            A1[k] = (int)__builtin_amdgcn_perm((unsigned)r23[2 * k + 1], (unsigned)r23[2 * k], sel);
        }
        a0 = __builtin_bit_cast(f16x8, A0);
        a1 = __builtin_bit_cast(f16x8, A1);

#pragma unroll
        for (int n = 0; n < 4; ++n) pp[n] = pn[n];
        xc = xn;
    }

    // ---- epilogue: logits + fused loss (all in-wave, shfl-based)
    float part = 0.f;
#pragma unroll
    for (int n = 0; n < 4; ++n) part += hkeep[n] * Wfc[16 * n + cc];
#pragma unroll
    for (int off = 8; off > 0; off >>= 1) part += __shfl_down(part, off, 16);
    float rsum = __shfl(part, l & 48, 64);  // group (hi) lane-0 value
    float z = rsum + bfc[0];
    if (cc == 0) logits[b0 + hi] = z;
    float tg = targets[b0 + hi];
    float e = EXP2F(-1.44269504f * fabsf(z));
    float lsp = fminf(z, 0.0f) - log1pf(e);
    float lsn = lsp - z;
    float lp = -(POS_W * tg * lsp + (1.0f - tg) * lsn) * (1.0f / (float)B_);
    float s = 0.f;
#pragma unroll
    for (int qq = 0; qq < 4; ++qq) s += __shfl(lp, qq * 16, 64);
    if (l == 0) atomicAdd(loss_slot, s);
}

// ---------------------------------------------------------------------------
extern "C" void kernel_launch(void* const* d_in, const int* in_sizes, int n_in,
                              void* d_out, int out_size, void* d_ws, size_t ws_size,
                              hipStream_t stream) {
    const int* x = (const int*)d_in[0];
    const float* targets = (const float*)d_in[1];
    const float* emb = (const float*)d_in[2];
    const float* Wih = (const float*)d_in[3];
    const float* Whh = (const float*)d_in[4];
    const float* bih = (const float*)d_in[5];
    const float* bhh = (const float*)d_in[6];
    const float* Wfc = (const float*)d_in[7];
    const float* bfc = (const float*)d_in[8];
    float* out = (float*)d_out;  // [0..2047] logits, [2048] loss

    float* projC = (float*)d_ws;  // 128*256*4 = 128 KiB

    k_prep<<<dim3(V_), dim3(256), 0, stream>>>(emb, Wih, bih, bhh, projC, out + B_);
    k_lstm<<<dim3(NBLK_), dim3(64), 0, stream>>>(x, Whh, projC, Wfc, bfc, targets, out,
                                                 out + B_);
}

// Round 6
// 166.609 us; speedup vs baseline: 1.7324x; 1.7324x over previous
//
#include <hip/hip_runtime.h>
#include <stdint.h>

#define B_ 2048
#define T_ 256
#define V_ 128
#define E_ 128
#define H_ 64
#define G4_ 256  // 4*H
#define POS_W 20.0f
#define MB_ 8            // rows q -> M-row 4q (C-reg[0]), rows q+4 -> M-row 4q+1 (C-reg[1])
#define NBLK_ (B_ / MB_) // 256 blocks = 1 block/CU
typedef _Float16 half1;
typedef __attribute__((ext_vector_type(8))) _Float16 f16x8;
typedef __attribute__((ext_vector_type(4))) float f32x4;

#if __has_builtin(__builtin_amdgcn_exp2f)
#define EXP2F(x) __builtin_amdgcn_exp2f(x)
#else
#define EXP2F(x) exp2f(x)
#endif

#if __has_builtin(__builtin_amdgcn_rcpf)
#define RCPF(x) __builtin_amdgcn_rcpf(x)
#else
#define RCPF(x) (1.0f / (x))
#endif

#define L2E 1.44269504f

// Barrier draining ONLY lgkmcnt: keeps L2 proj-prefetches (vmcnt) in flight
// across the step boundary. Safe: h-exchange is double-buffered; in-flight
// global loads only write registers.
__device__ __forceinline__ void lds_barrier() {
    asm volatile("s_waitcnt lgkmcnt(0)\n\ts_barrier" ::: "memory");
}

// ---------------------------------------------------------------------------
// k_prep: projC[v][u][g] = dot(emb[v], W_ih[g*64+u]) + b_ih + b_hh   (f32)
// ---------------------------------------------------------------------------
__global__ void k_prep(const float* __restrict__ emb, const float* __restrict__ Wih,
                       const float* __restrict__ bih, const float* __restrict__ bhh,
                       float* __restrict__ projC, float* __restrict__ loss_slot) {
    int tid = threadIdx.x;  // 0..255; u = tid>>2, g = tid&3
    int v = blockIdx.x;
    if (v == 0 && tid == 0) *loss_slot = 0.0f;
    int u = tid >> 2, g = tid & 3;
    int row = g * 64 + u;
    const float4* e4 = (const float4*)(emb + v * E_);
    const float4* w4 = (const float4*)(Wih + row * E_);
    float acc = bih[row] + bhh[row];
#pragma unroll
    for (int i = 0; i < E_ / 4; ++i) {
        float4 a = e4[i];
        float4 b = w4[i];
        acc += a.x * b.x + a.y * b.y + a.z * b.z + a.w * b.w;
    }
    projC[v * G4_ + tid] = acc;  // coalesced
}

// ---------------------------------------------------------------------------
// k_lstm R14: shared-MFMA pairing (MB=8) + full chain/issue fixes.
// Per-SIMD-step ledger from R1/R4/R5 counters:
//   R4 (MB4,2blk/CU): 258 MFMA-pipe + 232 VALU + 400 stall = 890 cyc
//   R1 (MB8, shared): 129 MFMA-pipe + 427 VALU + 428 stall = 984 cyc
// Shared-MFMA halves MFMA pipe time (16x16x32 f16 ~19 SIMD-cyc each); R1's
// loss was chained MFMA pairs + un-interleaved sequential cell chains.
// Fixes here: unchained pairs w/ shared z4 C (no C-quad movs), pp prescaled
// into exp2 args (fma, issued in MFMA shadow), prefetch after MFMA issue,
// register token prefetch, manual A/B statement interleave in the cells.
// ---------------------------------------------------------------------------
__launch_bounds__(256, 1)
__global__ void k_lstm(const int* __restrict__ x, const float* __restrict__ Whh,
                       const float* __restrict__ projC, const float* __restrict__ Wfc,
                       const float* __restrict__ bfc, const float* __restrict__ targets,
                       float* __restrict__ logits, float* __restrict__ loss_slot) {
    int b0 = blockIdx.x * MB_;
    int t = threadIdx.x;         // 0..255
    int w = t >> 6, l = t & 63;  // wave, lane
    int q = l >> 4, cc = l & 15;
    int u = 16 * w + cc;  // unit owned by this lane (all 4 gates), rows q and q+4

    __shared__ __align__(16) half1 hf[2][1024];  // A-layout h, double-buffered
    __shared__ int xT[T_][MB_];                  // token byte-offsets (tok<<10)
    __shared__ float hfin[MB_][68];              // final h (padded)
    __shared__ float zred[MB_];

    // stage xT (coalesced: fixed i, consecutive t); pre-scale to byte offset
#pragma unroll
    for (int i = 0; i < MB_; ++i) xT[t][i] = x[(b0 + i) * T_ + t] << 10;  // *G4_*4
    ((float*)hf)[t] = 0.0f;
    ((float*)hf)[t + 256] = 0.0f;
    ((float*)hf)[t + 512] = 0.0f;
    ((float*)hf)[t + 768] = 0.0f;
    __syncthreads();

    // B-fragments inline from W_hh (f32, L2): N-tile jj, K-chunk c.
    // frag elem j: B[k=c*32+q*8+j][col cc] = Whh[jj*64+16w+cc][k]  (R5-R8 verified)
    f16x8 bf[4][2];
#pragma unroll
    for (int jj = 0; jj < 4; ++jj) {
#pragma unroll
        for (int c = 0; c < 2; ++c) {
            int row = jj * 64 + 16 * w + cc;
            int kb = c * 32 + q * 8;
            float4 w0 = *(const float4*)(Whh + row * H_ + kb);
            float4 w1 = *(const float4*)(Whh + row * H_ + kb + 4);
            f16x8 tmp;
            tmp[0] = (half1)w0.x; tmp[1] = (half1)w0.y;
            tmp[2] = (half1)w0.z; tmp[3] = (half1)w0.w;
            tmp[4] = (half1)w1.x; tmp[5] = (half1)w1.y;
            tmp[6] = (half1)w1.z; tmp[7] = (half1)w1.w;
            bf[jj][c] = tmp;
        }
    }

    // h-write slot for (unit u, M-row 4q); row 4q+1 (group B) is +8
    int hbase = (u >> 5) * 512 + ((u >> 3) & 3) * 128 + (4 * q) * 8 + (u & 7);

    float cA = 0.0f, hA = 0.0f;  // batch row q
    float cB = 0.0f, hB = 0.0f;  // batch row q+4
    const char* pcb = (const char*)projC;
    int uoff = u << 4;  // u*16 bytes

    // prefetch proj for steps 0 and 1 (depth 2)
    f32x4 ppA = *(const f32x4*)(pcb + xT[0][q] + uoff);
    f32x4 ppB = *(const f32x4*)(pcb + xT[0][q + 4] + uoff);
    f32x4 pnA = *(const f32x4*)(pcb + xT[1][q] + uoff);
    f32x4 pnB = *(const f32x4*)(pcb + xT[1][q + 4] + uoff);
    int xcA = xT[2][q];      // token byte-offset for step+2's proj load
    int xcB = xT[2][q + 4];

    const f32x4 z4 = {0.0f, 0.0f, 0.0f, 0.0f};
    int p = 0;
#pragma unroll 2
    for (int step = 0; step < T_; ++step) {
        // ---- chain head: A-fragments of h_t (conflict-free lane-contiguous b128)
        const f16x8 a0 = *(const f16x8*)(hf[p] + l * 8);
        const f16x8 a1 = *(const f16x8*)(hf[p] + 512 + l * 8);

        // 8 MFMAs, unchained pairs, shared z4 C (no per-MFMA C movs).
        // C-reg[0] = row q, C-reg[1] = row q+4.
        f32x4 d0[4], d1[4];
#pragma unroll
        for (int jj = 0; jj < 4; ++jj) {
            d0[jj] = __builtin_amdgcn_mfma_f32_16x16x32_f16(a0, bf[jj][0], z4, 0, 0, 0);
            d1[jj] = __builtin_amdgcn_mfma_f32_16x16x32_f16(a1, bf[jj][1], z4, 0, 0, 0);
        }

        // ---- off-chain, in MFMA shadow: prefetch + pp prescale
        f32x4 p2A = *(const f32x4*)(pcb + xcA + uoff);  // proj for step+2
        f32x4 p2B = *(const f32x4*)(pcb + xcB + uoff);
        int xnA = xT[(step + 3) & (T_ - 1)][q];         // token for step+3
        int xnB = xT[(step + 3) & (T_ - 1)][q + 4];
        float psAx = -L2E * ppA.x, psBx = -L2E * ppB.x;
        float psAy = -L2E * ppA.y, psBy = -L2E * ppB.y;
        float pgAz = 2.0f * L2E * ppA.z, pgBz = 2.0f * L2E * ppB.z;
        float psAw = -L2E * ppA.w, psBw = -L2E * ppB.w;

        // ---- chain tail: gate extraction + two cells, manually interleaved
        float gA0 = d0[0][0] + d1[0][0], gB0 = d0[0][1] + d1[0][1];
        float gA1 = d0[1][0] + d1[1][0], gB1 = d0[1][1] + d1[1][1];
        float gA2 = d0[2][0] + d1[2][0], gB2 = d0[2][1] + d1[2][1];
        float gA3 = d0[3][0] + d1[3][0], gB3 = d0[3][1] + d1[3][1];

        float eiA = EXP2F(__builtin_fmaf(-L2E, gA0, psAx));
        float eiB = EXP2F(__builtin_fmaf(-L2E, gB0, psBx));
        float efA = EXP2F(__builtin_fmaf(-L2E, gA1, psAy));
        float efB = EXP2F(__builtin_fmaf(-L2E, gB1, psBy));
        float egA = EXP2F(__builtin_fmaf(2.0f * L2E, gA2, pgAz));
        float egB = EXP2F(__builtin_fmaf(2.0f * L2E, gB2, pgBz));
        float eoA = EXP2F(__builtin_fmaf(-L2E, gA3, psAw));
        float eoB = EXP2F(__builtin_fmaf(-L2E, gB3, psBw));

        float iA = RCPF(1.0f + eiA), iB = RCPF(1.0f + eiB);
        float fA = RCPF(1.0f + efA), fB = RCPF(1.0f + efB);
        float tgA = 1.0f - 2.0f * RCPF(egA + 1.0f);
        float tgB = 1.0f - 2.0f * RCPF(egB + 1.0f);
        float oA = RCPF(1.0f + eoA), oB = RCPF(1.0f + eoB);

        cA = __builtin_fmaf(fA, cA, iA * tgA);
        cB = __builtin_fmaf(fB, cB, iB * tgB);
        float etA = EXP2F(2.0f * L2E * cA);
        float etB = EXP2F(2.0f * L2E * cB);
        hA = oA * (1.0f - 2.0f * RCPF(etA + 1.0f));
        hB = oB * (1.0f - 2.0f * RCPF(etB + 1.0f));

        // publish h_{t+1} (A-layout, other buffer)
        hf[p ^ 1][hbase] = (half1)hA;
        hf[p ^ 1][hbase + 8] = (half1)hB;

        ppA = pnA; ppB = pnB;
        pnA = p2A; pnB = p2B;
        xcA = xnA; xcB = xnB;
        p ^= 1;
        lds_barrier();  // lgkmcnt-only: proj prefetches stay in flight
    }

    // epilogue: logits + fused loss
    hfin[q][u] = hA;
    hfin[q + 4][u] = hB;
    __syncthreads();
    int m4 = t >> 6, uu = t & 63;  // wave m4 reduces batch rows m4 and m4+4
    float wv = Wfc[uu];
    float pa = hfin[m4][uu] * wv;
    float pb = hfin[m4 + 4][uu] * wv;
#pragma unroll
    for (int off = 32; off > 0; off >>= 1) {
        pa += __shfl_down(pa, off, 64);
        pb += __shfl_down(pb, off, 64);
    }
    if (uu == 0) {
        float z = pa + bfc[0];
        logits[b0 + m4] = z;
        float tg = targets[b0 + m4];
        float e = EXP2F(-L2E * fabsf(z));
        float lsp = fminf(z, 0.0f) - log1pf(e);
        float lsn = lsp - z;
        zred[m4] = -(POS_W * tg * lsp + (1.0f - tg) * lsn) * (1.0f / (float)B_);

        float z2 = pb + bfc[0];
        logits[b0 + m4 + 4] = z2;
        float tg2 = targets[b0 + m4 + 4];
        float e2 = EXP2F(-L2E * fabsf(z2));
        float lsp2 = fminf(z2, 0.0f) - log1pf(e2);
        float lsn2 = lsp2 - z2;
        zred[m4 + 4] = -(POS_W * tg2 * lsp2 + (1.0f - tg2) * lsn2) * (1.0f / (float)B_);
    }
    __syncthreads();
    if (t == 0) {
        float s = 0.0f;
#pragma unroll
        for (int i = 0; i < MB_; ++i) s += zred[i];
        atomicAdd(loss_slot, s);
    }
}

// ---------------------------------------------------------------------------
extern "C" void kernel_launch(void* const* d_in, const int* in_sizes, int n_in,
                              void* d_out, int out_size, void* d_ws, size_t ws_size,
                              hipStream_t stream) {
    const int* x = (const int*)d_in[0];
    const float* targets = (const float*)d_in[1];
    const float* emb = (const float*)d_in[2];
    const float* Wih = (const float*)d_in[3];
    const float* Whh = (const float*)d_in[4];
    const float* bih = (const float*)d_in[5];
    const float* bhh = (const float*)d_in[6];
    const float* Wfc = (const float*)d_in[7];
    const float* bfc = (const float*)d_in[8];
    float* out = (float*)d_out;  // [0..2047] logits, [2048] loss

    float* projC = (float*)d_ws;  // 128*256*4 = 128 KiB

    k_prep<<<dim3(V_), dim3(256), 0, stream>>>(emb, Wih, bih, bhh, projC, out + B_);
    k_lstm<<<dim3(NBLK_), dim3(256), 0, stream>>>(x, Whh, projC, Wfc, bfc, targets, out,
                                                  out + B_);
}